// Round 2
// baseline (658.964 us; speedup 1.0000x reference)
//
#include <hip/hip_runtime.h>
#include <hip/hip_bf16.h>
#include <math.h>

#define BB 2
#define SS 2048
#define DD 2048
#define HH 16
#define DHH 128
#define MM (BB*SS)   // 4096

typedef __attribute__((ext_vector_type(8))) short bf16x8;
typedef __attribute__((ext_vector_type(4))) float f32x4;

#define AS1 __attribute__((address_space(1)))
#define AS3 __attribute__((address_space(3)))
#define GLOAD_LDS16(g, l) __builtin_amdgcn_global_load_lds((const AS1 void*)(g), (AS3 void*)(l), 16, 0, 0)

__device__ __forceinline__ float b2f(short s) {
  union { unsigned int u; float f; } v;
  v.u = ((unsigned int)(unsigned short)s) << 16;
  return v.f;
}
__device__ __forceinline__ short f2b(float f) {
  union { float f; unsigned int u; } v; v.f = f;
  unsigned int u = v.u;
  u += 0x7fffu + ((u >> 16) & 1u);   // round-to-nearest-even
  return (short)(u >> 16);
}

// ---------------- fp32 -> bf16 convert ----------------
__global__ void cvt_f32_bf16(const float* __restrict__ in, short* __restrict__ out, int n4) {
  int i = blockIdx.x * blockDim.x + threadIdx.x;
  if (i >= n4) return;
  float4 v = ((const float4*)in)[i];
  short4 o;
  o.x = f2b(v.x); o.y = f2b(v.y); o.z = f2b(v.z); o.w = f2b(v.w);
  ((short4*)out)[i] = o;
}

// ---------------- GEMM: C[m,n] = sum_k A[m,k] * W[n,k] ----------------
// m97-style: global_load_lds width-16 staging, 128x128 tile, BK=64, unpadded LDS.
// MODE 0: write bf16 to [B,H,S,DH]  (m = b*S+s, n = h*DH+d)
// MODE 1: write fp32 to [Mtot,Ntot]
template<int MODE>
__global__ __launch_bounds__(256)
void gemm_bt(const short* __restrict__ A, const short* __restrict__ Bw,
             void* __restrict__ Cout, int K, int Ntot) {
  __shared__ __align__(16) short As[128*64];
  __shared__ __align__(16) short Bs[128*64];
  const int tid = threadIdx.x;
  const int lane = tid & 63;
  const int wave = tid >> 6;
  const int wm = wave >> 1, wn = wave & 1;
  const int quad = lane >> 4, l16 = lane & 15;
  const int bm = blockIdx.y * 128, bn = blockIdx.x * 128;

  // staging map: round j (0..3): row = j*32 + (tid>>3), col = (tid&7)*8 shorts (16B)
  const int srow = tid >> 3;        // 0..31
  const int scol = (tid & 7) * 8;   // shorts
  const short* aBase = A + (size_t)(bm + srow) * K + scol;
  const short* bBase = Bw + (size_t)(bn + srow) * K + scol;
  // LDS dest base for this wave, round j: shorts offset j*2048 + wave*512
  f32x4 acc[4][4] = {};

  for (int k0 = 0; k0 < K; k0 += 64) {
    #pragma unroll
    for (int j = 0; j < 4; ++j) {
      GLOAD_LDS16(aBase + (size_t)j * 32 * K + k0, As + j * 2048 + wave * 512);
      GLOAD_LDS16(bBase + (size_t)j * 32 * K + k0, Bs + j * 2048 + wave * 512);
    }
    __syncthreads();
    #pragma unroll
    for (int kk = 0; kk < 64; kk += 32) {
      bf16x8 af[4], bf[4];
      #pragma unroll
      for (int t = 0; t < 4; ++t)
        af[t] = *(const bf16x8*)&As[(wm*64 + t*16 + l16) * 64 + kk + quad*8];
      #pragma unroll
      for (int t = 0; t < 4; ++t)
        bf[t] = *(const bf16x8*)&Bs[(wn*64 + t*16 + l16) * 64 + kk + quad*8];
      #pragma unroll
      for (int mt = 0; mt < 4; ++mt)
        #pragma unroll
        for (int nt = 0; nt < 4; ++nt)
          acc[mt][nt] = __builtin_amdgcn_mfma_f32_16x16x32_bf16(af[mt], bf[nt], acc[mt][nt], 0, 0, 0);
    }
    __syncthreads();
  }

  #pragma unroll
  for (int mt = 0; mt < 4; ++mt) {
    #pragma unroll
    for (int nt = 0; nt < 4; ++nt) {
      #pragma unroll
      for (int r = 0; r < 4; ++r) {
        int m = bm + wm*64 + mt*16 + quad*4 + r;
        int n = bn + wn*64 + nt*16 + l16;
        float v = acc[mt][nt][r];
        if (MODE == 0) {
          int b = m >> 11, s = m & 2047;
          int h = n >> 7,  d = n & 127;
          ((short*)Cout)[(((size_t)(b*HH + h)*SS + s)*DHH) + d] = f2b(v);
        } else {
          ((float*)Cout)[(size_t)m * Ntot + n] = v;
        }
      }
    }
  }
}

// ---------------- RoPE (interleaved) on [B,H,S,DH] bf16, in place ----------------
__global__ void rope_kernel(short* __restrict__ T, const int* __restrict__ pos, int total) {
  int idx = blockIdx.x * blockDim.x + threadIdx.x;
  if (idx >= total) return;
  int g = idx & 15;                 // which 8-elem group in DH
  int rowid = idx >> 4;             // bh*S + s
  int s = rowid & (SS - 1);
  short* p = T + (size_t)rowid * DHH + g * 8;
  float fp = (float)pos[s];
  int4 raw = *(int4*)p;
  short* e = (short*)&raw;
  #pragma unroll
  for (int j = 0; j < 4; ++j) {
    int pi = g * 4 + j;             // pair index 0..63
    float fr = expf(-0.14391156831f * (float)pi);  // theta^(-pi/64)
    float ang = fp * fr;
    float sn, cs;
    sincosf(ang, &sn, &cs);
    float xe = b2f(e[2*j]), xo = b2f(e[2*j+1]);
    float oe = xe * cs - xo * sn;
    float oo = xe * sn + xo * cs;
    e[2*j]   = f2b(oe);
    e[2*j+1] = f2b(oo);
  }
  *(int4*)p = raw;
}

// ---------------- Flash attention (causal), 128-row Q tiles ----------------
// Q,K,V: bf16 [B,H,S,DH]; O: bf16 [B,S,D]
// Block: 256 thr (4 waves). Wave w owns q rows {mt*64 + w*16 + 0..15} for mt=0,1.
// KV tile: 64 keys. KP region aliases Ks (64x136) and Pb (4 waves x 32 x 72).
__global__ __launch_bounds__(256)
void attn(const short* __restrict__ Q, const short* __restrict__ K,
          const short* __restrict__ V, short* __restrict__ O) {
  __shared__ __align__(16) short KP[9216];    // 18432 B
  __shared__ __align__(16) short Vt[9216];    // [dim][key], stride 72 shorts
  const int tid = threadIdx.x;
  const int lane = tid & 63, wave = tid >> 6;
  const int quad = lane >> 4, l16 = lane & 15;
  const int qt = (int)gridDim.x - 1 - (int)blockIdx.x;   // heavy tiles first
  const int bh = blockIdx.y;
  const int b = bh >> 4, h = bh & 15;
  const int q0 = qt * 128;
  const short* KVbase_k = K + (size_t)bh * SS * DHH;
  const short* KVbase_v = V + (size_t)bh * SS * DHH;

  // Q fragments: aq[mt][ks], rows q0 + mt*64 + wave*16 + l16
  bf16x8 aq[2][4];
  #pragma unroll
  for (int mt = 0; mt < 2; ++mt) {
    const short* qp = Q + ((size_t)bh * SS + q0 + mt*64 + wave*16 + l16) * DHH + quad*8;
    #pragma unroll
    for (int ks = 0; ks < 4; ++ks) aq[mt][ks] = *(const bf16x8*)(qp + ks*32);
  }

  f32x4 o[2][8] = {};
  float mrow[2][4], lrow[2][4];
  #pragma unroll
  for (int mt = 0; mt < 2; ++mt)
    #pragma unroll
    for (int r = 0; r < 4; ++r) { mrow[mt][r] = -1e30f; lrow[mt][r] = 0.f; }

  // staging assignments
  const int krow = tid >> 2;          // 0..63
  const int kseg = (tid & 3) * 32;    // shorts
  const int vkp  = (tid & 31) * 2;    // key pair base 0..62
  const int vds  = (tid >> 5) * 16;   // dim segment 0..112
  const float scale = 0.08838834764831845f;  // 1/sqrt(128)

  const int nkt = 2*qt + 2;
  // prefetch tile 0
  int4 kreg[4], vreg[4];
  {
    const short* kp = KVbase_k + (size_t)krow * DHH + kseg;
    #pragma unroll
    for (int j = 0; j < 4; ++j) kreg[j] = *(const int4*)(kp + j*8);
    const short* vp = KVbase_v + (size_t)vkp * DHH + vds;
    vreg[0] = *(const int4*)(vp);
    vreg[1] = *(const int4*)(vp + 8);
    vreg[2] = *(const int4*)(vp + DHH);
    vreg[3] = *(const int4*)(vp + DHH + 8);
  }

  for (int kt = 0; kt < nkt; ++kt) {
    __syncthreads();   // A: prior Vt/KP reads done
    // write staged regs -> LDS
    #pragma unroll
    for (int j = 0; j < 4; ++j)
      *(int4*)&KP[krow*136 + kseg + j*8] = kreg[j];
    {
      const short* s0 = (const short*)&vreg[0];  // row vkp   dims vds..+15
      const short* s1 = (const short*)&vreg[2];  // row vkp+1
      #pragma unroll
      for (int e = 0; e < 16; ++e) {
        int val = (int)(unsigned short)s0[e] | ((int)(unsigned short)s1[e] << 16);
        *(int*)&Vt[(vds + e)*72 + vkp] = val;
      }
    }
    __syncthreads();   // B: LDS ready
    // prefetch next tile
    if (kt + 1 < nkt) {
      const short* kp = KVbase_k + (size_t)((kt+1)*64 + krow) * DHH + kseg;
      #pragma unroll
      for (int j = 0; j < 4; ++j) kreg[j] = *(const int4*)(kp + j*8);
      const short* vp = KVbase_v + (size_t)((kt+1)*64 + vkp) * DHH + vds;
      vreg[0] = *(const int4*)(vp);
      vreg[1] = *(const int4*)(vp + 8);
      vreg[2] = *(const int4*)(vp + DHH);
      vreg[3] = *(const int4*)(vp + DHH + 8);
    }

    // mt=0 tile fully masked iff kt*64 > q0 + wave*16 + 15 (mt=1 never fully masked)
    const int mstart = (kt*64 > q0 + wave*16 + 15) ? 1 : 0;

    float sv[2][4][4];
    #pragma unroll
    for (int mt = 0; mt < 2; ++mt) {
      if (mt < mstart) continue;
      const int rowmin = q0 + mt*64 + wave*16;
      const bool needmask = (kt*64 + 63 > rowmin);
      #pragma unroll
      for (int nt = 0; nt < 4; ++nt) {
        f32x4 a = {0.f, 0.f, 0.f, 0.f};
        #pragma unroll
        for (int ks = 0; ks < 4; ++ks) {
          bf16x8 bk = *(const bf16x8*)&KP[(nt*16 + l16)*136 + ks*32 + quad*8];
          a = __builtin_amdgcn_mfma_f32_16x16x32_bf16(aq[mt][ks], bk, a, 0, 0, 0);
        }
        int key = kt*64 + nt*16 + l16;
        #pragma unroll
        for (int r = 0; r < 4; ++r) {
          float sc = a[r] * scale;
          if (needmask && key > rowmin + quad*4 + r) sc = -1e30f;
          sv[mt][nt][r] = sc;
        }
      }
      // online softmax per row
      #pragma unroll
      for (int r = 0; r < 4; ++r) {
        float mx = fmaxf(fmaxf(sv[mt][0][r], sv[mt][1][r]), fmaxf(sv[mt][2][r], sv[mt][3][r]));
        #pragma unroll
        for (int off = 1; off < 16; off <<= 1)
          mx = fmaxf(mx, __shfl_xor(mx, off, 64));
        float mnew = fmaxf(mrow[mt][r], mx);
        float alpha = __expf(mrow[mt][r] - mnew);
        float ls = 0.f;
        #pragma unroll
        for (int nt = 0; nt < 4; ++nt) {
          float pv = __expf(sv[mt][nt][r] - mnew);
          sv[mt][nt][r] = pv; ls += pv;
        }
        #pragma unroll
        for (int off = 1; off < 16; off <<= 1)
          ls += __shfl_xor(ls, off, 64);
        lrow[mt][r] = lrow[mt][r] * alpha + ls;
        mrow[mt][r] = mnew;
        #pragma unroll
        for (int t = 0; t < 8; ++t) o[mt][t][r] *= alpha;
      }
    }

    __syncthreads();   // C: all waves done reading Ks (KP) -> safe to write P
    // write P to own quarter of KP (stride 72), read back as A-frags (own data only)
    #pragma unroll
    for (int mt = 0; mt < 2; ++mt) {
      if (mt < mstart) continue;
      #pragma unroll
      for (int nt = 0; nt < 4; ++nt)
        #pragma unroll
        for (int r = 0; r < 4; ++r)
          KP[wave*2304 + (mt*16 + quad*4 + r)*72 + nt*16 + l16] = f2b(sv[mt][nt][r]);
    }
    #pragma unroll
    for (int mt = 0; mt < 2; ++mt) {
      if (mt < mstart) continue;
      #pragma unroll
      for (int k2 = 0; k2 < 2; ++k2) {
        bf16x8 ap = *(const bf16x8*)&KP[wave*2304 + (mt*16 + l16)*72 + k2*32 + quad*8];
        #pragma unroll
        for (int nt = 0; nt < 8; ++nt) {
          bf16x8 bv = *(const bf16x8*)&Vt[(nt*16 + l16)*72 + k2*32 + quad*8];
          o[mt][nt] = __builtin_amdgcn_mfma_f32_16x16x32_bf16(ap, bv, o[mt][nt], 0, 0, 0);
        }
      }
    }
  }

  // epilogue: O[b, q, h*128 + d] bf16
  #pragma unroll
  for (int mt = 0; mt < 2; ++mt) {
    #pragma unroll
    for (int nt = 0; nt < 8; ++nt) {
      #pragma unroll
      for (int r = 0; r < 4; ++r) {
        int q = q0 + mt*64 + wave*16 + quad*4 + r;
        float v = o[mt][nt][r] / lrow[mt][r];
        O[((size_t)(b*SS + q)) * DD + h*DHH + nt*16 + l16] = f2b(v);
      }
    }
  }
}

extern "C" void kernel_launch(void* const* d_in, const int* in_sizes, int n_in,
                              void* d_out, int out_size, void* d_ws, size_t ws_size,
                              hipStream_t stream) {
  const float* x  = (const float*)d_in[0];
  const int* pos  = (const int*)d_in[1];
  const float* Wq = (const float*)d_in[2];
  const float* Wk = (const float*)d_in[3];
  const float* Wv = (const float*)d_in[4];
  const float* Wo = (const float*)d_in[5];

  char* ws = (char*)d_ws;
  short* xb  = (short*)(ws);
  short* wqb = (short*)(ws + 16777216);
  short* wkb = (short*)(ws + 25165824);
  short* wvb = (short*)(ws + 33554432);
  short* wob = (short*)(ws + 41943040);
  short* Qb  = (short*)(ws + 50331648);
  short* Kb  = (short*)(ws + 67108864);
  short* Vb  = (short*)(ws + 83886080);
  short* Ob  = (short*)(ws + 100663296);

  int nx4 = BB*SS*DD/4;   // 2097152
  int nw4 = DD*DD/4;      // 1048576
  cvt_f32_bf16<<<nx4/256, 256, 0, stream>>>(x,  xb,  nx4);
  cvt_f32_bf16<<<nw4/256, 256, 0, stream>>>(Wq, wqb, nw4);
  cvt_f32_bf16<<<nw4/256, 256, 0, stream>>>(Wk, wkb, nw4);
  cvt_f32_bf16<<<nw4/256, 256, 0, stream>>>(Wv, wvb, nw4);
  cvt_f32_bf16<<<nw4/256, 256, 0, stream>>>(Wo, wob, nw4);

  dim3 gg(DD/128, MM/128);   // (16, 32)
  gemm_bt<0><<<gg, 256, 0, stream>>>(xb, wqb, Qb, DD, DD);
  gemm_bt<0><<<gg, 256, 0, stream>>>(xb, wkb, Kb, DD, DD);
  gemm_bt<0><<<gg, 256, 0, stream>>>(xb, wvb, Vb, DD, DD);

  int nrope = BB*HH*SS*16;   // 1048576
  rope_kernel<<<nrope/256, 256, 0, stream>>>(Qb, pos, nrope);
  rope_kernel<<<nrope/256, 256, 0, stream>>>(Kb, pos, nrope);

  dim3 ga(SS/128, BB*HH);    // (16, 32)
  attn<<<ga, 256, 0, stream>>>(Qb, Kb, Vb, Ob);

  gemm_bt<1><<<gg, 256, 0, stream>>>(Ob, wob, d_out, DD, DD);
}

// Round 4
// 495.612 us; speedup vs baseline: 1.3296x; 1.3296x over previous
//
#include <hip/hip_runtime.h>
#include <hip/hip_bf16.h>
#include <math.h>

#define BB 2
#define SS 2048
#define DD 2048
#define HH 16
#define DHH 128
#define MM (BB*SS)   // 4096

typedef __attribute__((ext_vector_type(8))) short bf16x8;
typedef __attribute__((ext_vector_type(4))) float f32x4;

#define AS1 __attribute__((address_space(1)))
#define AS3 __attribute__((address_space(3)))
#define GLOAD_LDS16(g, l) __builtin_amdgcn_global_load_lds((const AS1 void*)(g), (AS3 void*)(l), 16, 0, 0)

__device__ __forceinline__ float b2f(short s) {
  union { unsigned int u; float f; } v;
  v.u = ((unsigned int)(unsigned short)s) << 16;
  return v.f;
}
__device__ __forceinline__ short f2b(float f) {
  union { float f; unsigned int u; } v; v.f = f;
  unsigned int u = v.u;
  u += 0x7fffu + ((u >> 16) & 1u);   // round-to-nearest-even
  return (short)(u >> 16);
}

// ---- DPP 16-lane reductions (VALU pipe, no LDS ops) ----
template<int CTRL>
__device__ __forceinline__ float dppf(float x) {
  int xi = __builtin_bit_cast(int, x);
  int r = __builtin_amdgcn_update_dpp(0, xi, CTRL, 0xf, 0xf, true);
  return __builtin_bit_cast(float, r);
}
// reduce across the 16 lanes of a DPP row (l16 group)
__device__ __forceinline__ float rmax16(float x) {
  x = fmaxf(x, dppf<0xB1>(x));   // quad_perm xor1
  x = fmaxf(x, dppf<0x4E>(x));   // quad_perm xor2
  x = fmaxf(x, dppf<0x141>(x));  // row_half_mirror (== xor4 after quads reduced)
  x = fmaxf(x, dppf<0x140>(x));  // row_mirror (== xor8 after lower bits reduced)
  return x;
}
__device__ __forceinline__ float rsum16(float x) {
  x += dppf<0xB1>(x);
  x += dppf<0x4E>(x);
  x += dppf<0x141>(x);
  x += dppf<0x140>(x);
  return x;
}

// ---------------- fp32 -> bf16 convert ----------------
__global__ void cvt_f32_bf16(const float* __restrict__ in, short* __restrict__ out, int n4) {
  int i = blockIdx.x * blockDim.x + threadIdx.x;
  if (i >= n4) return;
  float4 v = ((const float4*)in)[i];
  short4 o;
  o.x = f2b(v.x); o.y = f2b(v.y); o.z = f2b(v.z); o.w = f2b(v.w);
  ((short4*)out)[i] = o;
}

// ---------------- Fused QKV GEMM: N = 6144 over three weight mats ----------------
// A: bf16 [M,K]; W*: bf16 [2048,K]; writes bf16 to Q/K/V in [B,H,S,DH]
__global__ __launch_bounds__(256)
void gemm_qkv(const short* __restrict__ A,
              const short* __restrict__ Wq, const short* __restrict__ Wk,
              const short* __restrict__ Wv,
              short* __restrict__ Qo, short* __restrict__ Ko, short* __restrict__ Vo) {
  __shared__ __align__(16) short As[128*64];
  __shared__ __align__(16) short Bs[128*64];
  const int tid = threadIdx.x;
  const int lane = tid & 63;
  const int wave = tid >> 6;
  const int wm = wave >> 1, wn = wave & 1;
  const int quad = lane >> 4, l16 = lane & 15;
  const int wsel = blockIdx.x >> 4;           // 0=Q 1=K 2=V
  const short* Bw = Wq; short* Cout = Qo;
  if (wsel == 1) { Bw = Wk; Cout = Ko; }
  else if (wsel == 2) { Bw = Wv; Cout = Vo; }
  const int bn = (blockIdx.x & 15) * 128;     // col within selected W
  const int bm = blockIdx.y * 128;
  const int K = DD;

  const int srow = tid >> 3;
  const int scol = (tid & 7) * 8;
  const short* aBase = A + (size_t)(bm + srow) * K + scol;
  const short* bBase = Bw + (size_t)(bn + srow) * K + scol;
  f32x4 acc[4][4] = {};

  for (int k0 = 0; k0 < K; k0 += 64) {
    #pragma unroll
    for (int j = 0; j < 4; ++j) {
      GLOAD_LDS16(aBase + (size_t)j * 32 * K + k0, As + j * 2048 + wave * 512);
      GLOAD_LDS16(bBase + (size_t)j * 32 * K + k0, Bs + j * 2048 + wave * 512);
    }
    __syncthreads();
    #pragma unroll
    for (int kk = 0; kk < 64; kk += 32) {
      bf16x8 af[4], bf[4];
      #pragma unroll
      for (int t = 0; t < 4; ++t)
        af[t] = *(const bf16x8*)&As[(wm*64 + t*16 + l16) * 64 + kk + quad*8];
      #pragma unroll
      for (int t = 0; t < 4; ++t)
        bf[t] = *(const bf16x8*)&Bs[(wn*64 + t*16 + l16) * 64 + kk + quad*8];
      #pragma unroll
      for (int mt = 0; mt < 4; ++mt)
        #pragma unroll
        for (int nt = 0; nt < 4; ++nt)
          acc[mt][nt] = __builtin_amdgcn_mfma_f32_16x16x32_bf16(af[mt], bf[nt], acc[mt][nt], 0, 0, 0);
    }
    __syncthreads();
  }

  #pragma unroll
  for (int mt = 0; mt < 4; ++mt)
    #pragma unroll
    for (int nt = 0; nt < 4; ++nt)
      #pragma unroll
      for (int r = 0; r < 4; ++r) {
        int m = bm + wm*64 + mt*16 + quad*4 + r;
        int n = bn + wn*64 + nt*16 + l16;
        int b = m >> 11, s = m & 2047;
        int h = n >> 7,  d = n & 127;
        Cout[(((size_t)(b*HH + h)*SS + s)*DHH) + d] = f2b(acc[mt][nt][r]);
      }
}

// ---------------- O-projection GEMM (fp32 out) ----------------
__global__ __launch_bounds__(256)
void gemm_o(const short* __restrict__ A, const short* __restrict__ Bw,
            float* __restrict__ Cout) {
  __shared__ __align__(16) short As[128*64];
  __shared__ __align__(16) short Bs[128*64];
  const int tid = threadIdx.x;
  const int lane = tid & 63;
  const int wave = tid >> 6;
  const int wm = wave >> 1, wn = wave & 1;
  const int quad = lane >> 4, l16 = lane & 15;
  const int bm = blockIdx.y * 128, bn = blockIdx.x * 128;
  const int K = DD;

  const int srow = tid >> 3;
  const int scol = (tid & 7) * 8;
  const short* aBase = A + (size_t)(bm + srow) * K + scol;
  const short* bBase = Bw + (size_t)(bn + srow) * K + scol;
  f32x4 acc[4][4] = {};

  for (int k0 = 0; k0 < K; k0 += 64) {
    #pragma unroll
    for (int j = 0; j < 4; ++j) {
      GLOAD_LDS16(aBase + (size_t)j * 32 * K + k0, As + j * 2048 + wave * 512);
      GLOAD_LDS16(bBase + (size_t)j * 32 * K + k0, Bs + j * 2048 + wave * 512);
    }
    __syncthreads();
    #pragma unroll
    for (int kk = 0; kk < 64; kk += 32) {
      bf16x8 af[4], bf[4];
      #pragma unroll
      for (int t = 0; t < 4; ++t)
        af[t] = *(const bf16x8*)&As[(wm*64 + t*16 + l16) * 64 + kk + quad*8];
      #pragma unroll
      for (int t = 0; t < 4; ++t)
        bf[t] = *(const bf16x8*)&Bs[(wn*64 + t*16 + l16) * 64 + kk + quad*8];
      #pragma unroll
      for (int mt = 0; mt < 4; ++mt)
        #pragma unroll
        for (int nt = 0; nt < 4; ++nt)
          acc[mt][nt] = __builtin_amdgcn_mfma_f32_16x16x32_bf16(af[mt], bf[nt], acc[mt][nt], 0, 0, 0);
    }
    __syncthreads();
  }

  #pragma unroll
  for (int mt = 0; mt < 4; ++mt)
    #pragma unroll
    for (int nt = 0; nt < 4; ++nt)
      #pragma unroll
      for (int r = 0; r < 4; ++r) {
        int m = bm + wm*64 + mt*16 + quad*4 + r;
        int n = bn + wn*64 + nt*16 + l16;
        Cout[(size_t)m * DD + n] = acc[mt][nt][r];
      }
}

// ---------------- RoPE (interleaved) on [B,H,S,DH] bf16, in place ----------------
__global__ void rope_kernel(short* __restrict__ T, const int* __restrict__ pos, int total) {
  int idx = blockIdx.x * blockDim.x + threadIdx.x;
  if (idx >= total) return;
  int g = idx & 15;
  int rowid = idx >> 4;
  int s = rowid & (SS - 1);
  short* p = T + (size_t)rowid * DHH + g * 8;
  float fp = (float)pos[s];
  int4 raw = *(int4*)p;
  short* e = (short*)&raw;
  #pragma unroll
  for (int j = 0; j < 4; ++j) {
    int pi = g * 4 + j;
    float fr = expf(-0.14391156831f * (float)pi);
    float ang = fp * fr;
    float sn, cs;
    sincosf(ang, &sn, &cs);
    float xe = b2f(e[2*j]), xo = b2f(e[2*j+1]);
    float oe = xe * cs - xo * sn;
    float oo = xe * sn + xo * cs;
    e[2*j]   = f2b(oe);
    e[2*j+1] = f2b(oo);
  }
  *(int4*)p = raw;
}

// ---------------- Flash attention (causal), paired 64-row Q tiles ----------------
// Block p handles Q tiles qa=p and qb=31-p, sharing one KV staging stream.
// Per block: exactly 33 tile-computes regardless of p (load-balanced).
__global__ __launch_bounds__(256, 2)
void attn(const short* __restrict__ Q, const short* __restrict__ K,
          const short* __restrict__ V, short* __restrict__ O) {
  __shared__ __align__(16) short Ks[64*136];    // [key][dim], stride 136
  __shared__ __align__(16) short Vt[128*72];    // [dim][key], stride 72
  __shared__ __align__(16) short Pb[4*32*72];   // per-wave P, 2 tiles x 16 rows
  const int tid = threadIdx.x;
  const int lane = tid & 63, wave = tid >> 6;
  const int quad = lane >> 4, l16 = lane & 15;
  const int p = blockIdx.x;            // 0..15
  const int qa = p, qb = 31 - p;
  const int bh = blockIdx.y;
  const int b = bh >> 4, h = bh & 15;
  const short* Kg = K + (size_t)bh * SS * DHH;
  const short* Vg = V + (size_t)bh * SS * DHH;

  // Q fragments: t=0 -> tile qa, t=1 -> tile qb
  bf16x8 aq[2][4];
  #pragma unroll
  for (int t = 0; t < 2; ++t) {
    int qrb = (t ? qb : qa) * 64;
    const short* qp = Q + ((size_t)bh * SS + qrb + wave*16 + l16) * DHH + quad*8;
    #pragma unroll
    for (int ks = 0; ks < 4; ++ks) aq[t][ks] = *(const bf16x8*)(qp + ks*32);
  }

  f32x4 o[2][8] = {};
  float mrow[2][4], lrow[2][4];
  #pragma unroll
  for (int t = 0; t < 2; ++t)
    #pragma unroll
    for (int r = 0; r < 4; ++r) { mrow[t][r] = -1e30f; lrow[t][r] = 0.f; }

  const int krow = tid >> 2;          // 0..63
  const int kseg = (tid & 3) * 32;    // shorts
  const int vkp  = (tid & 31) * 2;    // key pair 0..62
  const int vds  = (tid >> 5) * 16;   // dim segment
  const float scale = 0.08838834764831845f;

  const int nkt = qb + 1;             // 17..32
  int4 kreg[4], vreg[4];
  {
    const short* kp = Kg + (size_t)krow * DHH + kseg;
    #pragma unroll
    for (int j = 0; j < 4; ++j) kreg[j] = *(const int4*)(kp + j*8);
    const short* vp = Vg + (size_t)vkp * DHH + vds;
    vreg[0] = *(const int4*)(vp);
    vreg[1] = *(const int4*)(vp + 8);
    vreg[2] = *(const int4*)(vp + DHH);
    vreg[3] = *(const int4*)(vp + DHH + 8);
  }

  for (int kt = 0; kt < nkt; ++kt) {
    // ---- stage regs -> LDS ----
    #pragma unroll
    for (int j = 0; j < 4; ++j)
      *(int4*)&Ks[krow*136 + kseg + j*8] = kreg[j];
    {
      const short* s0 = (const short*)&vreg[0];
      const short* s1 = (const short*)&vreg[2];
      #pragma unroll
      for (int e = 0; e < 16; ++e) {
        int val = (int)(unsigned short)s0[e] | ((int)(unsigned short)s1[e] << 16);
        *(int*)&Vt[(vds + e)*72 + vkp] = val;
      }
    }
    __syncthreads();   // staging visible

    // ---- prefetch next tile into regs (overlaps compute) ----
    if (kt + 1 < nkt) {
      const short* kp = Kg + (size_t)((kt+1)*64 + krow) * DHH + kseg;
      #pragma unroll
      for (int j = 0; j < 4; ++j) kreg[j] = *(const int4*)(kp + j*8);
      const short* vp = Vg + (size_t)((kt+1)*64 + vkp) * DHH + vds;
      vreg[0] = *(const int4*)(vp);
      vreg[1] = *(const int4*)(vp + 8);
      vreg[2] = *(const int4*)(vp + DHH);
      vreg[3] = *(const int4*)(vp + DHH + 8);
    }

    const bool actA = (kt <= qa);

    // ---- QK^T: bk fragments loaded once, used for both tiles ----
    float sv[2][4][4];
    #pragma unroll
    for (int nt = 0; nt < 4; ++nt) {
      f32x4 a1 = {0.f,0.f,0.f,0.f}, a0 = {0.f,0.f,0.f,0.f};
      #pragma unroll
      for (int ks = 0; ks < 4; ++ks) {
        bf16x8 bk = *(const bf16x8*)&Ks[(nt*16 + l16)*136 + ks*32 + quad*8];
        a1 = __builtin_amdgcn_mfma_f32_16x16x32_bf16(aq[1][ks], bk, a1, 0, 0, 0);
        if (actA) a0 = __builtin_amdgcn_mfma_f32_16x16x32_bf16(aq[0][ks], bk, a0, 0, 0, 0);
      }
      #pragma unroll
      for (int r = 0; r < 4; ++r) {
        sv[1][nt][r] = a1[r] * scale;
        sv[0][nt][r] = a0[r] * scale;
      }
    }
    // causal mask (only the diagonal tile of each Q-tile needs it)
    #pragma unroll
    for (int t = 0; t < 2; ++t) {
      int tq = t ? qb : qa;
      if (kt == tq) {
        #pragma unroll
        for (int nt = 0; nt < 4; ++nt)
          #pragma unroll
          for (int r = 0; r < 4; ++r)
            if (nt*16 + l16 > wave*16 + quad*4 + r) sv[t][nt][r] = -1e30f;
      }
    }

    // ---- online softmax (DPP reductions, VALU only) + P write ----
    #pragma unroll
    for (int t = 0; t < 2; ++t) {
      if (t == 0 && !actA) continue;
      #pragma unroll
      for (int r = 0; r < 4; ++r) {
        float mx = fmaxf(fmaxf(sv[t][0][r], sv[t][1][r]), fmaxf(sv[t][2][r], sv[t][3][r]));
        mx = rmax16(mx);
        float mnew = fmaxf(mrow[t][r], mx);
        float alpha = __expf(mrow[t][r] - mnew);
        float ls = 0.f;
        #pragma unroll
        for (int nt = 0; nt < 4; ++nt) {
          float pv = __expf(sv[t][nt][r] - mnew);
          sv[t][nt][r] = pv; ls += pv;
        }
        ls = rsum16(ls);
        lrow[t][r] = lrow[t][r] * alpha + ls;
        mrow[t][r] = mnew;
        #pragma unroll
        for (int nt = 0; nt < 8; ++nt) o[t][nt][r] *= alpha;
      }
      #pragma unroll
      for (int nt = 0; nt < 4; ++nt)
        #pragma unroll
        for (int r = 0; r < 4; ++r)
          Pb[wave*2304 + (t*16 + quad*4 + r)*72 + nt*16 + l16] = f2b(sv[t][nt][r]);
    }

    // ---- PV: bv fragments loaded once, used for both tiles ----
    bf16x8 ap[2][2];
    #pragma unroll
    for (int t = 0; t < 2; ++t)
      #pragma unroll
      for (int k2 = 0; k2 < 2; ++k2)
        ap[t][k2] = *(const bf16x8*)&Pb[wave*2304 + (t*16 + l16)*72 + k2*32 + quad*8];
    #pragma unroll
    for (int k2 = 0; k2 < 2; ++k2) {
      #pragma unroll
      for (int nt = 0; nt < 8; ++nt) {
        bf16x8 bv = *(const bf16x8*)&Vt[(nt*16 + l16)*72 + k2*32 + quad*8];
        o[1][nt] = __builtin_amdgcn_mfma_f32_16x16x32_bf16(ap[1][k2], bv, o[1][nt], 0, 0, 0);
        if (actA) o[0][nt] = __builtin_amdgcn_mfma_f32_16x16x32_bf16(ap[0][k2], bv, o[0][nt], 0, 0, 0);
      }
    }
    __syncthreads();   // all reads done before next-iter staging writes
  }

  // ---- epilogue: O[b, q, h*128 + d] bf16 ----
  #pragma unroll
  for (int t = 0; t < 2; ++t) {
    int qrb = (t ? qb : qa) * 64;
    #pragma unroll
    for (int nt = 0; nt < 8; ++nt)
      #pragma unroll
      for (int r = 0; r < 4; ++r) {
        int q = qrb + wave*16 + quad*4 + r;
        float v = o[t][nt][r] / lrow[t][r];
        O[((size_t)(b*SS + q)) * DD + h*DHH + nt*16 + l16] = f2b(v);
      }
  }
}

extern "C" void kernel_launch(void* const* d_in, const int* in_sizes, int n_in,
                              void* d_out, int out_size, void* d_ws, size_t ws_size,
                              hipStream_t stream) {
  const float* x  = (const float*)d_in[0];
  const int* pos  = (const int*)d_in[1];
  const float* Wq = (const float*)d_in[2];
  const float* Wk = (const float*)d_in[3];
  const float* Wv = (const float*)d_in[4];
  const float* Wo = (const float*)d_in[5];

  char* ws = (char*)d_ws;
  short* xb  = (short*)(ws);
  short* wqb = (short*)(ws + 16777216);
  short* wkb = (short*)(ws + 25165824);
  short* wvb = (short*)(ws + 33554432);
  short* wob = (short*)(ws + 41943040);
  short* Qb  = (short*)(ws + 50331648);
  short* Kb  = (short*)(ws + 67108864);
  short* Vb  = (short*)(ws + 83886080);
  short* Ob  = (short*)(ws + 100663296);

  int nx4 = BB*SS*DD/4;
  int nw4 = DD*DD/4;
  cvt_f32_bf16<<<nx4/256, 256, 0, stream>>>(x,  xb,  nx4);
  cvt_f32_bf16<<<nw4/256, 256, 0, stream>>>(Wq, wqb, nw4);
  cvt_f32_bf16<<<nw4/256, 256, 0, stream>>>(Wk, wkb, nw4);
  cvt_f32_bf16<<<nw4/256, 256, 0, stream>>>(Wv, wvb, nw4);
  cvt_f32_bf16<<<nw4/256, 256, 0, stream>>>(Wo, wob, nw4);

  dim3 gq(48, MM/128);       // fused QKV: 1536 blocks
  gemm_qkv<<<gq, 256, 0, stream>>>(xb, wqb, wkb, wvb, Qb, Kb, Vb);

  int nrope = BB*HH*SS*16;
  rope_kernel<<<nrope/256, 256, 0, stream>>>(Qb, pos, nrope);
  rope_kernel<<<nrope/256, 256, 0, stream>>>(Kb, pos, nrope);

  dim3 ga(16, BB*HH);        // paired tiles: 512 balanced blocks
  attn<<<ga, 256, 0, stream>>>(Qb, Kb, Vb, Ob);

  dim3 go(DD/128, MM/128);
  gemm_o<<<go, 256, 0, stream>>>(Ob, wob, (float*)d_out);
}